// Round 3
// baseline (566.037 us; speedup 1.0000x reference)
//
#include <hip/hip_runtime.h>
#include <stdint.h>

// ---------------------------------------------------------------------------
// OrthoLinear: out[b,s,o] = sum_k x[b,s,k] * (dequant(base_packed,scales)[o,k]
//                                             + w_ortho[o,k])
// M = B*S = 8192, N = OUT = 4096, K = IN = 4096, fp32 in/out.
// R6 = R5 + fixed LDS swizzle for 32-row fragment reads.
//   R5's conflict (2.5e7): chunk XOR s(row)=(row>>1)&3 has period 8 in row,
//   so lanes 16 apart (rows 16 apart, same kh) hit the same 16B slot -> 4-way
//   pileup on slots {0,1,4,5}. Fix: s(row) = ((row>>1)&3) ^ (((row>>4)&1)<<1)
//   -> rows 16 apart use complementary chunk sets. Checked groupings:
//   8-consecutive lanes: 8 distinct slots; 16-consecutive: 2x each (free);
//   strided quads {l,l+16,l+32,l+48}: 2x each (free).
//   Staging source permutation updated to the same involution (rule #21).
//   Everything else identical to R5 (32x32x16 MFMA, 256x256 tile, 4-deep
//   ring, counted vmcnt(8), setprio, XCD-bijective block swizzle).
// ---------------------------------------------------------------------------

#define M_TOTAL 8192
#define N_TOTAL 4096
#define K_TOTAL 4096

typedef __attribute__((ext_vector_type(8)))  __bf16          bf16x8;   // MFMA A/B frag (4 VGPRs)
typedef __attribute__((ext_vector_type(16))) float           floatx16; // MFMA C/D frag (32x32)
typedef __attribute__((ext_vector_type(8)))  unsigned short  ushort8;
typedef __attribute__((ext_vector_type(4)))  float           f32x4;
typedef __attribute__((ext_vector_type(4)))  int             intx4;

// fp32 -> bf16 round-to-nearest-even (data has no NaN)
__device__ __forceinline__ unsigned short f2bf(float f) {
    union { float f; uint32_t u; } c; c.f = f;
    uint32_t u = c.u + 0x7FFFu + ((c.u >> 16) & 1u);
    return (unsigned short)(u >> 16);
}

// ---------------------------------------------------------------------------
// Merged prep (byte-identical to R3/R4/R5 — control variable).
// ---------------------------------------------------------------------------
#define CVT_BLOCKS 16384
#define DEQ_BLOCKS 8192

__global__ __launch_bounds__(256) void prep_kernel(
    const float* __restrict__ x,        // [M, K] fp32
    const int*   __restrict__ packed,   // [N, K/2] nibble-packed
    const float* __restrict__ scales,   // [N]
    const float* __restrict__ ortho,    // [N, K] fp32
    unsigned short* __restrict__ xb,    // [M, K] bf16 out
    unsigned short* __restrict__ wb)    // [N, K] bf16 out
{
    const int blk = blockIdx.x;
    if (blk < CVT_BLOCKS) {
        const size_t t = (size_t)blk * 256 + threadIdx.x;
        const f32x4* xv = (const f32x4*)x;
        f32x4 v0 = xv[2 * t];
        f32x4 v1 = xv[2 * t + 1];
        ushort8 r;
        r[0] = f2bf(v0[0]); r[1] = f2bf(v0[1]); r[2] = f2bf(v0[2]); r[3] = f2bf(v0[3]);
        r[4] = f2bf(v1[0]); r[5] = f2bf(v1[1]); r[6] = f2bf(v1[2]); r[7] = f2bf(v1[3]);
        ((ushort8*)xb)[t] = r;
    } else {
        const int t  = (blk - CVT_BLOCKS) * 256 + threadIdx.x;  // 0 .. N*(K/2)/4
        const int o  = t >> 9;                                  // 512 threads/row
        const int jp = (t & 511) << 2;                          // packed col base
        intx4 p = *(const intx4*)(packed + (size_t)o * (K_TOTAL / 2) + jp);
        const float s = scales[o];
        const size_t base = (size_t)o * K_TOTAL + (size_t)jp * 2;
        f32x4 g0 = *(const f32x4*)(ortho + base);
        f32x4 g1 = *(const f32x4*)(ortho + base + 4);
        float g[8] = { g0[0], g0[1], g0[2], g0[3], g1[0], g1[1], g1[2], g1[3] };
        ushort8 r;
#pragma unroll
        for (int i = 0; i < 4; ++i) {
            int pi = p[i];
            float lo = (float)((pi & 0xF) - 8) * s + g[2 * i];
            float hi = (float)(((pi >> 4) & 0xF) - 8) * s + g[2 * i + 1];
            r[2 * i]     = f2bf(lo);
            r[2 * i + 1] = f2bf(hi);
        }
        *(ushort8*)(wb + base) = r;
    }
}

// ---------------------------------------------------------------------------
// GEMM: C[M,N] = A[M,K](bf16) @ B[N,K](bf16)^T, fp32 accumulate.
// ---------------------------------------------------------------------------
__device__ __forceinline__ void async16(const void* g, void* l) {
    __builtin_amdgcn_global_load_lds(
        (__attribute__((address_space(1))) void*)(g),
        (__attribute__((address_space(3))) void*)(l),
        16, 0, 0);
}

#define MFMA32(a, b, c) __builtin_amdgcn_mfma_f32_32x32x16_bf16((a), (b), (c), 0, 0, 0)

__global__ __launch_bounds__(512, 2) void gemm256_kernel(
    const unsigned short* __restrict__ A,   // [M,K] bf16
    const unsigned short* __restrict__ Bm,  // [N,K] bf16
    float* __restrict__ C)                  // [M,N] fp32
{
    // 4 ring slots per matrix; slot = [256 rows][32 cols] bf16 = 8192 elems.
    __shared__ __attribute__((aligned(16))) unsigned short As[4 * 8192];
    __shared__ __attribute__((aligned(16))) unsigned short Bs[4 * 8192];

    const int tid  = threadIdx.x;
    const int wave = tid >> 6;
    const int lane = tid & 63;
    const int l31  = lane & 31;
    const int kh   = lane >> 5;      // k-half selector for 32x32x16 frags
    const int wm   = wave >> 2;      // 0..1  : wave M index (128 rows each)
    const int wn   = wave & 3;       // 0..3  : wave N index (64 cols each)

    // XCD-bijective swizzle: grid is (16,32) = 512 blocks, 512 % 8 == 0.
    const int orig = blockIdx.y * 16 + blockIdx.x;
    const int lin  = (orig & 7) * 64 + (orig >> 3);
    const int row0 = (lin >> 4) * 256;   // M origin
    const int col0 = (lin & 15) * 256;   // N origin

    // --- staging source (pre-swizzled: gload_lds dest is linear base+lane*16)
    // instruction covers 128 rows x 32 cols (8 KB); thread t -> row t>>2,
    // dest chunk t&3; source chunk = (t&3) ^ s(row),
    // s(row) = ((row>>1)&3) ^ (((row>>4)&1)<<1)
    //        = ((t>>3)&3) ^ (((t>>6)&1)<<1) in thread bits.
    // Both 128-row halves reduce to the same lane formula (row+128 leaves the
    // swizzle bits of row unchanged).
    const int sr = tid >> 2;                       // 0..127
    const int cs = (tid & 3) ^ ((tid >> 3) & 3) ^ (((tid >> 6) & 1) << 1);
    const unsigned short* ag0 = A  + (size_t)(row0 + sr) * K_TOTAL + cs * 8;
    const unsigned short* ag1 = ag0 + (size_t)128 * K_TOTAL;
    const unsigned short* bg0 = Bm + (size_t)(col0 + sr) * K_TOTAL + cs * 8;
    const unsigned short* bg1 = bg0 + (size_t)128 * K_TOTAL;

    unsigned short* AsW = As + wave * 512;   // wave's 1 KB slice of each 8 KB half
    unsigned short* BsW = Bs + wave * 512;

#define STAGE_A(slot, kk) do { \
    async16(ag0 + (kk), AsW + (slot) * 8192); \
    async16(ag1 + (kk), AsW + (slot) * 8192 + 4096); } while (0)
#define STAGE_B(slot, kk) do { \
    async16(bg0 + (kk), BsW + (slot) * 8192); \
    async16(bg1 + (kk), BsW + (slot) * 8192 + 4096); } while (0)

    // --- fragment reads: row stride 32 elems (64 B); chunk read back through
    // the same XOR. Frag row = base + l31 with base ≡ 0 mod 32, so
    // s(row) = ((l31>>1)&3) ^ (((l31>>4)&1)<<1). Logical chunk = 2*h + kh.
    const int swz = ((l31 >> 1) & 3) ^ (((l31 >> 4) & 1) << 1);
#define AOFS(mi, h) ((wm * 128 + (mi) * 32 + l31) * 32 + (((((h) << 1) + kh) ^ swz) << 3))
#define BOFS(ni, h) ((wn * 64  + (ni) * 32 + l31) * 32 + (((((h) << 1) + kh) ^ swz) << 3))
#define LDSA(slot, mi, h) (*(const bf16x8*)(As + (slot) * 8192 + AOFS(mi, h)))
#define LDSB(slot, ni, h) (*(const bf16x8*)(Bs + (slot) * 8192 + BOFS(ni, h)))

    floatx16 acc[4][2] = {};

    // One K=32 slice = 2 phases (k-half 0, k-half 1), 8 MFMA each.
#define SLICE(slot, DOSTAGE, kkst, VMW) do { \
    bf16x8 b00 = LDSB(slot, 0, 0), b10 = LDSB(slot, 1, 0); \
    bf16x8 a00 = LDSA(slot, 0, 0), a10 = LDSA(slot, 1, 0); \
    bf16x8 a20 = LDSA(slot, 2, 0), a30 = LDSA(slot, 3, 0); \
    if (DOSTAGE) STAGE_A(((slot) + 3) & 3, kkst); \
    __builtin_amdgcn_s_barrier(); \
    asm volatile("s_waitcnt lgkmcnt(0)"); \
    __builtin_amdgcn_s_setprio(1); \
    acc[0][0] = MFMA32(a00, b00, acc[0][0]); acc[0][1] = MFMA32(a00, b10, acc[0][1]); \
    acc[1][0] = MFMA32(a10, b00, acc[1][0]); acc[1][1] = MFMA32(a10, b10, acc[1][1]); \
    acc[2][0] = MFMA32(a20, b00, acc[2][0]); acc[2][1] = MFMA32(a20, b10, acc[2][1]); \
    acc[3][0] = MFMA32(a30, b00, acc[3][0]); acc[3][1] = MFMA32(a30, b10, acc[3][1]); \
    __builtin_amdgcn_s_setprio(0); \
    __builtin_amdgcn_s_barrier(); \
    bf16x8 b01 = LDSB(slot, 0, 1), b11 = LDSB(slot, 1, 1); \
    bf16x8 a01 = LDSA(slot, 0, 1), a11 = LDSA(slot, 1, 1); \
    bf16x8 a21 = LDSA(slot, 2, 1), a31 = LDSA(slot, 3, 1); \
    if (DOSTAGE) STAGE_B(((slot) + 3) & 3, kkst); \
    __builtin_amdgcn_s_barrier(); \
    asm volatile("s_waitcnt lgkmcnt(0)"); \
    __builtin_amdgcn_s_setprio(1); \
    acc[0][0] = MFMA32(a01, b01, acc[0][0]); acc[0][1] = MFMA32(a01, b11, acc[0][1]); \
    acc[1][0] = MFMA32(a11, b01, acc[1][0]); acc[1][1] = MFMA32(a11, b11, acc[1][1]); \
    acc[2][0] = MFMA32(a21, b01, acc[2][0]); acc[2][1] = MFMA32(a21, b11, acc[2][1]); \
    acc[3][0] = MFMA32(a31, b01, acc[3][0]); acc[3][1] = MFMA32(a31, b11, acc[3][1]); \
    __builtin_amdgcn_s_setprio(0); \
    asm volatile(VMW); \
    __builtin_amdgcn_s_barrier(); \
} while (0)

    // Prologue: fill the 4-slot ring (16 loads/wave), wait for slice 0 only.
    STAGE_A(0, 0);  STAGE_B(0, 0);
    STAGE_A(1, 32); STAGE_B(1, 32);
    STAGE_A(2, 64); STAGE_B(2, 64);
    STAGE_A(3, 96); STAGE_B(3, 96);
    asm volatile("s_waitcnt vmcnt(12)");
    __builtin_amdgcn_s_barrier();

    // Slices 0..3: slice 0 stages nothing (its target, slice 3, is prestaged).
    SLICE(0, 0, 0,      "s_waitcnt vmcnt(8)");
    SLICE(1, 1, 4 * 32, "s_waitcnt vmcnt(8)");
    SLICE(2, 1, 5 * 32, "s_waitcnt vmcnt(8)");
    SLICE(3, 1, 6 * 32, "s_waitcnt vmcnt(8)");

    // Steady state: slices 4..123, staging slices 7..126, vmcnt(8) per slice.
#pragma unroll 1
    for (int s4 = 4; s4 <= 120; s4 += 4) {
        const int kkb = (s4 + 3) * 32;
        SLICE(0, 1, kkb,      "s_waitcnt vmcnt(8)");
        SLICE(1, 1, kkb + 32, "s_waitcnt vmcnt(8)");
        SLICE(2, 1, kkb + 64, "s_waitcnt vmcnt(8)");
        SLICE(3, 1, kkb + 96, "s_waitcnt vmcnt(8)");
    }

    // Tail: slice 124 stages the last slice (127); drain 8 -> 4 -> 0.
    SLICE(0, 1, 127 * 32, "s_waitcnt vmcnt(8)");
    SLICE(1, 0, 0,        "s_waitcnt vmcnt(4)");
    SLICE(2, 0, 0,        "s_waitcnt vmcnt(0)");
    SLICE(3, 0, 0,        "");

#undef SLICE
#undef LDSA
#undef LDSB
#undef AOFS
#undef BOFS
#undef STAGE_A
#undef STAGE_B

    // Epilogue. 32x32 C/D layout (m74/m101-verified):
    // col = lane&31, row = (reg&3) + 8*(reg>>2) + 4*(lane>>5), reg in [0,16).
    const int c_col = col0 + wn * 64 + l31;
#pragma unroll
    for (int mi = 0; mi < 4; ++mi) {
#pragma unroll
        for (int ni = 0; ni < 2; ++ni) {
            const int rb = row0 + wm * 128 + mi * 32 + 4 * kh;
            const int cc = c_col + ni * 32;
#pragma unroll
            for (int g = 0; g < 4; ++g)
#pragma unroll
                for (int j = 0; j < 4; ++j)
                    C[(size_t)(rb + 8 * g + j) * N_TOTAL + cc] = acc[mi][ni][4 * g + j];
        }
    }
}

// ---------------------------------------------------------------------------
extern "C" void kernel_launch(void* const* d_in, const int* in_sizes, int n_in,
                              void* d_out, int out_size, void* d_ws, size_t ws_size,
                              hipStream_t stream) {
    const float* x      = (const float*)d_in[0];   // [4,2048,4096] fp32
    const int*   packed = (const int*)d_in[1];     // [4096,2048] int32
    const float* scales = (const float*)d_in[2];   // [4096,1] fp32
    const float* ortho  = (const float*)d_in[3];   // [4096,4096] fp32
    float*       out    = (float*)d_out;           // [4,2048,4096] fp32

    // Workspace layout: Xb (bf16, 64 MB) | Wb (bf16, 32 MB) = 96 MB total
    unsigned short* Xb = (unsigned short*)d_ws;
    unsigned short* Wb = (unsigned short*)((char*)d_ws + (size_t)M_TOTAL * K_TOTAL * 2);

    prep_kernel<<<CVT_BLOCKS + DEQ_BLOCKS, 256, 0, stream>>>(x, packed, scales, ortho, Xb, Wb);

    dim3 grid(N_TOTAL / 256, M_TOTAL / 256);  // (16, 32) = 512 blocks
    gemm256_kernel<<<grid, 512, 0, stream>>>(Xb, Wb, out);
}

// Round 4
// 537.791 us; speedup vs baseline: 1.0525x; 1.0525x over previous
//
#include <hip/hip_runtime.h>
#include <stdint.h>

// ---------------------------------------------------------------------------
// OrthoLinear: out[b,s,o] = sum_k x[b,s,k] * (dequant(base_packed,scales)[o,k]
//                                             + w_ortho[o,k])
// M = B*S = 8192, N = OUT = 4096, K = IN = 4096, fp32 in/out.
// R7 = R4 (verified 257us: 16x16x32 MFMA, 256x256 tile, chunk-XOR swizzle,
//      0 bank conflicts, no XCD swizzle) + single-barrier slice schedule.
//   R5/R6 (32x32 MFMA) abandoned: 2.5e7 conflicts, immune to two swizzle
//   theories (identical count) -> unmodeled HW behavior, reverted.
//   Schedule change: R4 spent 4 s_barrier + 2 full lgkmcnt(0) drains per
//   K=32 slice. Slot data is stable all slice, so mid-slice barriers are
//   pure overhead. New slice: {12 ds_read + 4 gload_lds issue; 32 MFMA with
//   compiler-managed PARTIAL lgkm waits (a4..a7 stay outstanding under the
//   first 16 MFMA); vmcnt(8); s_barrier; sched_barrier(0)}.
//   Race audit: barrier bounds drift to <1 slice; a wave's slice-s reads are
//   in regs before its closing barrier (compiler waits before last consuming
//   MFMA); stage in slice s+1 overwrites slot s&3 only after that barrier.
//   Cross-wave gload_lds visibility: own vmcnt(8) precedes the barrier.
// ---------------------------------------------------------------------------

#define M_TOTAL 8192
#define N_TOTAL 4096
#define K_TOTAL 4096

typedef __attribute__((ext_vector_type(8)))  __bf16          bf16x8;   // MFMA A/B frag (4 VGPRs)
typedef __attribute__((ext_vector_type(4)))  float           floatx4;  // MFMA C/D frag
typedef __attribute__((ext_vector_type(8)))  unsigned short  ushort8;
typedef __attribute__((ext_vector_type(4)))  float           f32x4;
typedef __attribute__((ext_vector_type(4)))  int             intx4;

// fp32 -> bf16 round-to-nearest-even (data has no NaN)
__device__ __forceinline__ unsigned short f2bf(float f) {
    union { float f; uint32_t u; } c; c.f = f;
    uint32_t u = c.u + 0x7FFFu + ((c.u >> 16) & 1u);
    return (unsigned short)(u >> 16);
}

// ---------------------------------------------------------------------------
// Merged prep (byte-identical since R3 — control variable).
// ---------------------------------------------------------------------------
#define CVT_BLOCKS 16384
#define DEQ_BLOCKS 8192

__global__ __launch_bounds__(256) void prep_kernel(
    const float* __restrict__ x,        // [M, K] fp32
    const int*   __restrict__ packed,   // [N, K/2] nibble-packed
    const float* __restrict__ scales,   // [N]
    const float* __restrict__ ortho,    // [N, K] fp32
    unsigned short* __restrict__ xb,    // [M, K] bf16 out
    unsigned short* __restrict__ wb)    // [N, K] bf16 out
{
    const int blk = blockIdx.x;
    if (blk < CVT_BLOCKS) {
        const size_t t = (size_t)blk * 256 + threadIdx.x;
        const f32x4* xv = (const f32x4*)x;
        f32x4 v0 = xv[2 * t];
        f32x4 v1 = xv[2 * t + 1];
        ushort8 r;
        r[0] = f2bf(v0[0]); r[1] = f2bf(v0[1]); r[2] = f2bf(v0[2]); r[3] = f2bf(v0[3]);
        r[4] = f2bf(v1[0]); r[5] = f2bf(v1[1]); r[6] = f2bf(v1[2]); r[7] = f2bf(v1[3]);
        ((ushort8*)xb)[t] = r;
    } else {
        const int t  = (blk - CVT_BLOCKS) * 256 + threadIdx.x;  // 0 .. N*(K/2)/4
        const int o  = t >> 9;                                  // 512 threads/row
        const int jp = (t & 511) << 2;                          // packed col base
        intx4 p = *(const intx4*)(packed + (size_t)o * (K_TOTAL / 2) + jp);
        const float s = scales[o];
        const size_t base = (size_t)o * K_TOTAL + (size_t)jp * 2;
        f32x4 g0 = *(const f32x4*)(ortho + base);
        f32x4 g1 = *(const f32x4*)(ortho + base + 4);
        float g[8] = { g0[0], g0[1], g0[2], g0[3], g1[0], g1[1], g1[2], g1[3] };
        ushort8 r;
#pragma unroll
        for (int i = 0; i < 4; ++i) {
            int pi = p[i];
            float lo = (float)((pi & 0xF) - 8) * s + g[2 * i];
            float hi = (float)(((pi >> 4) & 0xF) - 8) * s + g[2 * i + 1];
            r[2 * i]     = f2bf(lo);
            r[2 * i + 1] = f2bf(hi);
        }
        *(ushort8*)(wb + base) = r;
    }
}

// ---------------------------------------------------------------------------
// GEMM: C[M,N] = A[M,K](bf16) @ B[N,K](bf16)^T, fp32 accumulate.
// 256x256 tile, 8 waves (2M x 4N), per-wave 128x64, acc[8][4] of 16x16.
// 4-deep ring of K=32 slices; ONE barrier per slice.
// ---------------------------------------------------------------------------
__device__ __forceinline__ void async16(const void* g, void* l) {
    __builtin_amdgcn_global_load_lds(
        (__attribute__((address_space(1))) void*)(g),
        (__attribute__((address_space(3))) void*)(l),
        16, 0, 0);
}

__global__ __launch_bounds__(512, 2) void gemm256_kernel(
    const unsigned short* __restrict__ A,   // [M,K] bf16
    const unsigned short* __restrict__ Bm,  // [N,K] bf16
    float* __restrict__ C)                  // [M,N] fp32
{
    // 4 ring slots per matrix; slot = [256 rows][32 cols] bf16 = 8192 elems.
    __shared__ __attribute__((aligned(16))) unsigned short As[4 * 8192];
    __shared__ __attribute__((aligned(16))) unsigned short Bs[4 * 8192];

    const int tid  = threadIdx.x;
    const int wave = tid >> 6;
    const int lane = tid & 63;
    const int quad = lane >> 4;
    const int r16  = lane & 15;
    const int wm   = wave >> 2;      // 0..1  : wave M index (128 rows each)
    const int wn   = wave & 3;       // 0..3  : wave N index (64 cols each)

    const int row0 = blockIdx.y * 256;   // M origin
    const int col0 = blockIdx.x * 256;   // N origin

    // --- staging source (pre-swizzled: gload_lds dest is linear base+lane*16)
    // instruction covers 128 rows x 32 cols (8 KB); thread t -> row t>>2,
    // dest chunk t&3; source chunk = (t&3) ^ ((row>>1)&3) = (t&3)^((t>>3)&3).
    const int sr = tid >> 2;                       // 0..127
    const int cs = (tid & 3) ^ ((tid >> 3) & 3);   // swizzled source chunk
    const unsigned short* ag0 = A  + (size_t)(row0 + sr) * K_TOTAL + cs * 8;
    const unsigned short* ag1 = ag0 + (size_t)128 * K_TOTAL;
    const unsigned short* bg0 = Bm + (size_t)(col0 + sr) * K_TOTAL + cs * 8;
    const unsigned short* bg1 = bg0 + (size_t)128 * K_TOTAL;

    unsigned short* AsW = As + wave * 512;   // wave's 1 KB slice of each 8 KB half
    unsigned short* BsW = Bs + wave * 512;

#define STAGE_A(slot, kk) do { \
    async16(ag0 + (kk), AsW + (slot) * 8192); \
    async16(ag1 + (kk), AsW + (slot) * 8192 + 4096); } while (0)
#define STAGE_B(slot, kk) do { \
    async16(bg0 + (kk), BsW + (slot) * 8192); \
    async16(bg1 + (kk), BsW + (slot) * 8192 + 4096); } while (0)

    // --- fragment reads: row stride 32 elems (64 B); chunk read back through
    // the same XOR; frag row offsets (mi*16, wm*128) are ≡0 mod the swizzle
    // period, so the lane's swizzle term is constant. (R4-verified, 0 confl.)
    const int swz   = (r16 >> 1) & 3;
    const int a_ofs = (wm * 128 + r16) * 32 + ((quad ^ swz) << 3);
    const int b_ofs = (wn * 64  + r16) * 32 + ((quad ^ swz) << 3);

#define LDA(slot, m) (*(const bf16x8*)(As + (slot) * 8192 + a_ofs + (m) * 512))
#define LDB(slot, n) (*(const bf16x8*)(Bs + (slot) * 8192 + b_ofs + (n) * 512))

    floatx4 acc[8][4] = {};

#define MROW(mi, ar) \
    acc[mi][0] = __builtin_amdgcn_mfma_f32_16x16x32_bf16(ar, b0, acc[mi][0], 0, 0, 0); \
    acc[mi][1] = __builtin_amdgcn_mfma_f32_16x16x32_bf16(ar, b1, acc[mi][1], 0, 0, 0); \
    acc[mi][2] = __builtin_amdgcn_mfma_f32_16x16x32_bf16(ar, b2, acc[mi][2], 0, 0, 0); \
    acc[mi][3] = __builtin_amdgcn_mfma_f32_16x16x32_bf16(ar, b3, acc[mi][3], 0, 0, 0);

    // One K=32 slice, ONE barrier. All 12 ds_reads issue up front; the
    // compiler's partial lgkm waits let a4..a7 stay outstanding under the
    // first 16 MFMAs. Stage of slice s+3 (slot (s+3)&3) issues here — its
    // slot's readers finished at the END of slice s-1 (previous barrier).
    // VMW (counted, never 0 in steady state) precedes the barrier so that
    // after the barrier ALL waves' loads for slice s+1 are complete.
#define SLICE(slot, DOSTAGE, kkst, VMW) do { \
    bf16x8 b0 = LDB(slot, 0), b1 = LDB(slot, 1), b2 = LDB(slot, 2), b3 = LDB(slot, 3); \
    bf16x8 a0 = LDA(slot, 0), a1 = LDA(slot, 1), a2 = LDA(slot, 2), a3 = LDA(slot, 3); \
    bf16x8 a4 = LDA(slot, 4), a5 = LDA(slot, 5), a6 = LDA(slot, 6), a7 = LDA(slot, 7); \
    if (DOSTAGE) { STAGE_A(((slot) + 3) & 3, kkst); STAGE_B(((slot) + 3) & 3, kkst); } \
    __builtin_amdgcn_s_setprio(1); \
    MROW(0, a0) MROW(1, a1) MROW(2, a2) MROW(3, a3) \
    MROW(4, a4) MROW(5, a5) MROW(6, a6) MROW(7, a7) \
    __builtin_amdgcn_s_setprio(0); \
    asm volatile(VMW); \
    __builtin_amdgcn_s_barrier(); \
    __builtin_amdgcn_sched_barrier(0); \
} while (0)

    // Prologue: fill the 4-slot ring (16 loads/wave), wait for slice 0 only.
    STAGE_A(0, 0);  STAGE_B(0, 0);
    STAGE_A(1, 32); STAGE_B(1, 32);
    STAGE_A(2, 64); STAGE_B(2, 64);
    STAGE_A(3, 96); STAGE_B(3, 96);
    asm volatile("s_waitcnt vmcnt(12)");
    __builtin_amdgcn_s_barrier();
    __builtin_amdgcn_sched_barrier(0);

    // Slices 0..3: slice 0 stages nothing (its target, slice 3, is prestaged).
    SLICE(0, 0, 0,      "s_waitcnt vmcnt(8)");
    SLICE(1, 1, 4 * 32, "s_waitcnt vmcnt(8)");
    SLICE(2, 1, 5 * 32, "s_waitcnt vmcnt(8)");
    SLICE(3, 1, 6 * 32, "s_waitcnt vmcnt(8)");

    // Steady state: slices 4..123, staging slices 7..126, vmcnt(8) per slice.
#pragma unroll 1
    for (int s4 = 4; s4 <= 120; s4 += 4) {
        const int kkb = (s4 + 3) * 32;
        SLICE(0, 1, kkb,      "s_waitcnt vmcnt(8)");
        SLICE(1, 1, kkb + 32, "s_waitcnt vmcnt(8)");
        SLICE(2, 1, kkb + 64, "s_waitcnt vmcnt(8)");
        SLICE(3, 1, kkb + 96, "s_waitcnt vmcnt(8)");
    }

    // Tail: slice 124 stages the last slice (127); drain 8 -> 4 -> 0.
    SLICE(0, 1, 127 * 32, "s_waitcnt vmcnt(8)");
    SLICE(1, 0, 0,        "s_waitcnt vmcnt(4)");
    SLICE(2, 0, 0,        "s_waitcnt vmcnt(0)");
    SLICE(3, 0, 0,        "s_nop 0");

#undef SLICE
#undef MROW
#undef LDA
#undef LDB
#undef STAGE_A
#undef STAGE_B

    // Epilogue. C/D layout (m89/m91-verified): col = lane&15, row = quad*4+reg.
#pragma unroll
    for (int mi = 0; mi < 8; ++mi) {
#pragma unroll
        for (int ni = 0; ni < 4; ++ni) {
            const int r = row0 + wm * 128 + mi * 16 + quad * 4;
            const int c = col0 + wn * 64 + ni * 16 + r16;
#pragma unroll
            for (int i = 0; i < 4; ++i)
                C[(size_t)(r + i) * N_TOTAL + c] = acc[mi][ni][i];
        }
    }
}

// ---------------------------------------------------------------------------
extern "C" void kernel_launch(void* const* d_in, const int* in_sizes, int n_in,
                              void* d_out, int out_size, void* d_ws, size_t ws_size,
                              hipStream_t stream) {
    const float* x      = (const float*)d_in[0];   // [4,2048,4096] fp32
    const int*   packed = (const int*)d_in[1];     // [4096,2048] int32
    const float* scales = (const float*)d_in[2];   // [4096,1] fp32
    const float* ortho  = (const float*)d_in[3];   // [4096,4096] fp32
    float*       out    = (float*)d_out;           // [4,2048,4096] fp32

    // Workspace layout: Xb (bf16, 64 MB) | Wb (bf16, 32 MB) = 96 MB total
    unsigned short* Xb = (unsigned short*)d_ws;
    unsigned short* Wb = (unsigned short*)((char*)d_ws + (size_t)M_TOTAL * K_TOTAL * 2);

    prep_kernel<<<CVT_BLOCKS + DEQ_BLOCKS, 256, 0, stream>>>(x, packed, scales, ortho, Xb, Wb);

    dim3 grid(N_TOTAL / 256, M_TOTAL / 256);  // (16, 32) = 512 blocks
    gemm256_kernel<<<grid, 512, 0, stream>>>(Xb, Wb, out);
}